// Round 8
// baseline (72.348 us; speedup 1.0000x reference)
//
#include <hip/hip_runtime.h>
#include <hip/hip_bf16.h>
#include <stdint.h>

typedef __attribute__((ext_vector_type(8))) short short8;
typedef __attribute__((ext_vector_type(4))) float float4_t;

#define N_PTS 1024
#define G_DIM 620
#define G_PAD 640
#define F_DIM 20
#define H_DIM 150
#define H_PAD 160
#define K_WIN 128
#define OUT_C (K_WIN + 1)

__device__ __forceinline__ float bf2f(short u) {
  union { unsigned int i; float f; } x;
  x.i = ((unsigned int)(unsigned short)u) << 16;
  return x.f;
}
__device__ __forceinline__ short f2bf(float f) {
  union { float f; unsigned int i; } x; x.f = f;
  unsigned int u = x.i;
  u += 0x7FFFu + ((u >> 16) & 1u);   // RNE
  return (short)(u >> 16);
}
__device__ __forceinline__ short f2bf_hw(float f) {
  __hip_bfloat16 h = __float2bfloat16(f);
  union { __hip_bfloat16 h; short s; } u; u.h = h;
  return u.s;
}
__device__ __forceinline__ void gload_lds16(const void* g, void* l) {
  __builtin_amdgcn_global_load_lds(
      (const __attribute__((address_space(1))) unsigned int*)g,
      (__attribute__((address_space(3))) unsigned int*)l, 16, 0, 0);
}

// ---------------------------------------------------------------------------
// prep_pack: grid 321 x 256 (unchanged from r7).
// ---------------------------------------------------------------------------
__global__ void prep_pack(const float* __restrict__ g, const float* __restrict__ W1,
                          const float* __restrict__ W2, const float* __restrict__ dist_emb,
                          short* __restrict__ g_bf, short* __restrict__ W1cT,
                          short* __restrict__ W1abT, short* __restrict__ W2T,
                          float* __restrict__ deW) {
  __shared__ float lds[32 * 165];
  const int bx = blockIdx.x, tid = threadIdx.x;
  if (bx < 256) {
    const int n0 = bx * 4;
    for (int c = tid; c < 320; c += 256) {
      int r = c / 80, cc = c - r * 80;
      int n = n0 + r, d0 = cc * 8;
      short8 o;
      if (d0 + 8 <= G_DIM) {
        const float* src = g + n * G_DIM + d0;
        #pragma unroll
        for (int e = 0; e < 8; ++e) o[e] = f2bf(src[e]);
      } else {
        #pragma unroll
        for (int e = 0; e < 8; ++e) {
          int d = d0 + e;
          o[e] = (d < G_DIM) ? f2bf(g[n * G_DIM + d]) : (short)0;
        }
      }
      *(short8*)(g_bf + n * G_PAD + d0) = o;
    }
  } else if (bx < 316) {
    const int tb = bx - 256;
    const int third = tb / 20, dt = tb - third * 20;
    const int d0 = dt * 32;
    for (int c = tid; c < 1280; c += 256) {
      int dr = c / 40, ch4 = c - dr * 40;
      int dd = d0 + dr;
      int w1r = third * G_DIM + dd;
      #pragma unroll
      for (int e = 0; e < 4; ++e) {
        int h = ch4 * 4 + e;
        lds[dr * 165 + h] = (dd < G_DIM && h < H_DIM) ? W1[w1r * H_DIM + h] : 0.f;
      }
    }
    __syncthreads();
    short* outp = (third == 2) ? W1cT : (W1abT + third * H_PAD * G_PAD);
    for (int c = tid; c < 640; c += 256) {
      int h = c >> 2, ch = c & 3;
      short8 o;
      #pragma unroll
      for (int e = 0; e < 8; ++e) o[e] = f2bf(lds[(ch * 8 + e) * 165 + h]);
      *(short8*)(outp + h * G_PAD + d0 + ch * 8) = o;
    }
  } else if (bx < 320) {
    const int base = (bx - 316) * 6400;
    for (int c = tid; c < 6400; c += 256) {
      int q = base + c;
      int m = q / H_PAD, k = q - m * H_PAD;
      W2T[q] = (m < H_DIM && k < H_DIM) ? f2bf(W2[k * H_DIM + m]) : (short)0;
    }
  } else {
    for (int c = tid; c < 9 * H_PAD; c += 256) {
      int b = c / H_PAD, h = c - b * H_PAD;
      float acc = 0.f;
      if (h < H_DIM)
        for (int f = 0; f < F_DIM; ++f)
          acc += dist_emb[b * F_DIM + f] * W1[(3 * G_DIM + f) * H_DIM + h];
      deW[c] = acc;
    }
  }
}

// ---------------------------------------------------------------------------
// prep_uv_mfma: grid (37, 2).
//  x<32 : y=0 -> U (f32,+b1) ; y=1 -> V (f32). 32 rows/block (as r7).
//  x>=32: W1cF packers — step s = (x-32)+5*y. Fragment-major repack of W1cT:
//         chunk c = s*20 + (ks*2+wn)*5 + nt ; W1cF[c*512 + lane*8 + e] =
//         W1cT[wn*80+nt*16+(lane&15)][s*64+ks*32+(lane>>4)*8+e]
// ---------------------------------------------------------------------------
__global__ __launch_bounds__(256) void prep_uv_mfma(
    const short* __restrict__ g_bf, const short* __restrict__ W1abT,
    const short* __restrict__ W1cT, const float* __restrict__ b1,
    float* __restrict__ U, float* __restrict__ V, short* __restrict__ W1cF) {
  if (blockIdx.x >= 32) {                       // ---- W1cF packer ----
    const int s = (blockIdx.x - 32) + 5 * blockIdx.y;   // 0..9
    const int tid = threadIdx.x;
    #pragma unroll
    for (int it = 0; it < 5; ++it) {
      int slot = tid + 256 * it;                // 0..1279
      int lc = slot >> 6, lane = slot & 63;
      int ks = lc / 10, wn = (lc / 5) & 1, nt = lc % 5;
      int lo4 = lane & 15, hi2 = lane >> 4;
      short8 v = *(const short8*)(W1cT + (wn * 80 + nt * 16 + lo4) * G_PAD +
                                  s * 64 + ks * 32 + hi2 * 8);
      *(short8*)(W1cF + (s * 20 + lc) * 512 + lane * 8) = v;
    }
    return;
  }
  __shared__ __align__(16) char sA[32 * 128];
  __shared__ __align__(16) char sB[160 * 128];
  const int m0 = blockIdx.x * 32;
  const int yb = blockIdx.y * H_PAD;
  const int tid = threadIdx.x, lane = tid & 63, wid = tid >> 6;
  const int wm = wid >> 1, wn = wid & 1;
  const int lo4 = lane & 15, hi2 = lane >> 4;
  const int l8 = lane >> 3, c8 = lane & 7;
  const int xe = (c8 ^ (l8 & 7)) * 8;

  const float4_t fz = {0.f, 0.f, 0.f, 0.f};
  float4_t acc[5];
  #pragma unroll
  for (int b = 0; b < 5; ++b) acc[b] = fz;

  for (int step = 0; step < 10; ++step) {
    const int d0 = step * 64;
    {
      int row = wid * 8 + l8;
      gload_lds16(g_bf + (m0 + row) * G_PAD + d0 + xe, sA + (wid * 8) * 128);
    }
    #pragma unroll
    for (int cc = 0; cc < 5; ++cc) {
      int row = wid * 8 + cc * 32 + l8;
      gload_lds16(W1abT + (yb + row) * G_PAD + d0 + xe, sB + (wid * 8 + cc * 32) * 128);
    }
    __syncthreads();
    #pragma unroll
    for (int ks = 0; ks < 2; ++ks) {
      const int kb = ks * 64 + 16 * hi2;
      short8 af, bq[5];
      {
        int row = wm * 16 + lo4;
        af = *((const short8*)(sA + row * 128 + (kb ^ ((row & 7) << 4))));
      }
      #pragma unroll
      for (int nt = 0; nt < 5; ++nt) {
        int row = wn * 80 + nt * 16 + lo4;
        bq[nt] = *((const short8*)(sB + row * 128 + (kb ^ ((row & 7) << 4))));
      }
      #pragma unroll
      for (int nt = 0; nt < 5; ++nt)
        acc[nt] = __builtin_amdgcn_mfma_f32_16x16x32_bf16(af, bq[nt], acc[nt], 0, 0, 0);
    }
    __syncthreads();
  }

  const bool isU = (blockIdx.y == 0);
  float* O = isU ? U : V;
  #pragma unroll
  for (int r = 0; r < 4; ++r) {
    int m = m0 + wm * 16 + hi2 * 4 + r;
    #pragma unroll
    for (int nt = 0; nt < 5; ++nt) {
      int h = wn * 80 + nt * 16 + lo4;
      float v = acc[nt][r];
      if (h < H_DIM) { if (isU) v += b1[h]; } else { v = 0.f; }
      O[m * H_PAD + h] = v;
    }
  }
}

// ---------------------------------------------------------------------------
// pair_main: one block per i (XCD swizzle), 4 waves (2M x 2N), 2 blocks/CU.
// Layer1: P = gj.*gi staged coalesced->LDS (dbuf, only LDS user);
//         B = W1cF fragment-major COALESCED register loads, ping-pong
//         prefetched one full step ahead. 1 barrier/step.
// Layer2: h1(LDS swz) @ W2T(direct global, reg dbuf).
// ---------------------------------------------------------------------------
__global__ __launch_bounds__(256, 2) void pair_main(
    const short* __restrict__ g_bf, const short* __restrict__ W1cF,
    const short* __restrict__ W2T, const float* __restrict__ U,
    const float* __restrict__ V, const float* __restrict__ deW,
    const float* __restrict__ si, const int* __restrict__ i1,
    const int* __restrict__ i2, const float* __restrict__ W3,
    const float* __restrict__ b2, const float* __restrict__ b3,
    float* __restrict__ out) {
  __shared__ __align__(16) char smem[49152];     // P0|P1 (32KB) / Hb (48KB)
  __shared__ __align__(16) short gi_s[G_PAD];
  __shared__ float sj_s[K_WIN];
  __shared__ unsigned char bin_su[K_WIN];
  __shared__ float s_buf[2][K_WIN];

  char* const P0 = smem;              // 16 KB
  char* const P1 = smem + 16384;      // 16 KB
  char* const Hb = smem;              // 3 x 16 KB (aliases P0,P1 after L1)

  const int bid = blockIdx.x;
  const int i = ((bid & 7) << 7) | (bid >> 3);   // XCD-bijective swizzle
  const int tid = threadIdx.x;
  const int lane = tid & 63;
  const int wid = tid >> 6;
  const int wm = wid >> 1, wn = wid & 1;
  const int lo4 = lane & 15, hi2 = lane >> 4;
  const int tc8 = tid & 7;

  // ---- preamble ----
  if (tid < G_PAD / 8)
    ((short8*)gi_s)[tid] = ((const short8*)(g_bf + i * G_PAD))[tid];
  if (tid < K_WIN) {
    int jr = i - K_WIN + tid, jc = jr < 0 ? 0 : jr;
    int d = i2[i] - i1[jc];
    bin_su[tid] = (unsigned char)((d >= 1) + (d >= 2) + (d >= 3) + (d >= 4) +
                                  (d >= 8) + (d >= 16) + (d >= 32) + (d >= 64));
    sj_s[tid] = si[jc];
  }
  __syncthreads();

  const short8* const bfp = (const short8*)W1cF;

  auto loadBq = [&](int s, short8 (&bq)[2][5]) {
    #pragma unroll
    for (int ks = 0; ks < 2; ++ks)
      #pragma unroll
      for (int nt = 0; nt < 5; ++nt)
        bq[ks][nt] = bfp[(s * 20 + (ks * 2 + wn) * 5 + nt) * 64 + lane];
  };
  auto loadA = [&](int s, short8 (&gjv)[4], short8& gvv) {
    const int d0 = s * 64;
    gvv = *((const short8*)(gi_s + d0 + tc8 * 8));
    #pragma unroll
    for (int cc = 0; cc < 4; ++cc) {
      int c = tid + 256 * cc, row = c >> 3;
      int jr = i - K_WIN + row, jc = jr < 0 ? 0 : jr;
      gjv[cc] = *((const short8*)(g_bf + jc * G_PAD + d0 + tc8 * 8));
    }
  };
  auto writeP = [&](char* P, const short8 (&gjv)[4], const short8& gvv) {
    #pragma unroll
    for (int cc = 0; cc < 4; ++cc) {
      int c = tid + 256 * cc, row = c >> 3;
      short8 p;
      #pragma unroll
      for (int e = 0; e < 8; ++e) p[e] = f2bf_hw(bf2f(gjv[cc][e]) * bf2f(gvv[e]));
      int byte = row * 128 + ((tc8 * 16) ^ ((row & 7) << 4));
      *((short8*)(P + byte)) = p;
    }
  };

  const float4_t fz = {0.f, 0.f, 0.f, 0.f};
  float4_t acc[4][5];
  #pragma unroll
  for (int a = 0; a < 4; ++a)
    #pragma unroll
    for (int b = 0; b < 5; ++b) acc[a][b] = fz;

  auto mfma_step = [&](const char* Pc, const short8 (&bq)[2][5]) {
    __builtin_amdgcn_s_setprio(1);
    #pragma unroll
    for (int ks = 0; ks < 2; ++ks) {
      const int kb = ks * 64 + 16 * hi2;
      short8 af[4];
      #pragma unroll
      for (int mt = 0; mt < 4; ++mt) {
        int row = wm * 64 + mt * 16 + lo4;
        af[mt] = *((const short8*)(Pc + row * 128 + (kb ^ ((row & 7) << 4))));
      }
      #pragma unroll
      for (int mt = 0; mt < 4; ++mt)
        #pragma unroll
        for (int nt = 0; nt < 5; ++nt)
          acc[mt][nt] = __builtin_amdgcn_mfma_f32_16x16x32_bf16(af[mt], bq[ks][nt], acc[mt][nt], 0, 0, 0);
    }
    __builtin_amdgcn_s_setprio(0);
  };

  // ---- layer 1: 10 steps, ping-pong P + register B, 1 barrier/step ----
  short8 gjv[4], gvv;
  short8 bqE[2][5], bqO[2][5];
  loadA(0, gjv, gvv);
  loadBq(0, bqE);
  writeP(P0, gjv, gvv);

  #pragma unroll
  for (int ss = 0; ss < 5; ++ss) {
    const int s0 = 2 * ss;
    // even step s0 (P0, bqE)
    __syncthreads();
    loadA(s0 + 1, gjv, gvv);          // issue-early for next step
    loadBq(s0 + 1, bqO);
    mfma_step(P0, bqE);
    writeP(P1, gjv, gvv);             // write-late
    // odd step s0+1 (P1, bqO)
    __syncthreads();
    if (ss < 4) {
      loadA(s0 + 2, gjv, gvv);
      loadBq(s0 + 2, bqE);
      mfma_step(P1, bqO);
      writeP(P0, gjv, gvv);
    } else {
      mfma_step(P1, bqO);
    }
  }
  __syncthreads();   // layer-1 reads done; Hb may overwrite P0/P1

  // ---- epilogue 1: h1 = relu(acc + U[i] + V[j] + deW[bin]) -> Hb bf16 swz ----
  float uih[5];
  #pragma unroll
  for (int nt = 0; nt < 5; ++nt) uih[nt] = U[i * H_PAD + wn * 80 + nt * 16 + lo4];
  #pragma unroll
  for (int mt = 0; mt < 4; ++mt) {
    #pragma unroll
    for (int r = 0; r < 4; ++r) {
      int m = wm * 64 + mt * 16 + hi2 * 4 + r;
      int jr = i - K_WIN + m, jc = jr < 0 ? 0 : jr;
      const float* Vj = V + jc * H_PAD;
      const float* De = deW + bin_su[m] * H_PAD;
      #pragma unroll
      for (int nt = 0; nt < 5; ++nt) {
        int h = wn * 80 + nt * 16 + lo4;
        float val = acc[mt][nt][r] + uih[nt] + Vj[h] + De[h];
        val = (h < H_DIM) ? fmaxf(val, 0.f) : 0.f;
        int tile = h >> 6, hc = h & 63;
        int byte = tile * 16384 + m * 128 + ((hc * 2) ^ ((m & 7) << 4));
        *((short*)(Hb + byte)) = f2bf_hw(val);
      }
    }
  }
  // zero tile2 bytes 64..127 (XOR addressing touches them for k=128..159 reads)
  {
    short8 z = {0, 0, 0, 0, 0, 0, 0, 0};
    for (int c = tid; c < 512; c += 256) {
      int row = c >> 2, cb = c & 3;
      int byte = 2 * 16384 + row * 128 + ((64 + cb * 16) ^ ((row & 7) << 4));
      *((short8*)(Hb + byte)) = z;
    }
  }
  __syncthreads();

  // ---- layer 2: D2 = h1 @ W2 (K=160), B direct from global (L2), reg dbuf ----
  float4_t acc2[4][5];
  #pragma unroll
  for (int a = 0; a < 4; ++a)
    #pragma unroll
    for (int b = 0; b < 5; ++b) acc2[a][b] = fz;

  short8 bql[2][5];
  #pragma unroll
  for (int nt = 0; nt < 5; ++nt) {
    int row = wn * 80 + nt * 16 + lo4;
    bql[0][nt] = *(const short8*)(W2T + row * H_PAD + hi2 * 8);
  }
  #pragma unroll
  for (int ks = 0; ks < 5; ++ks) {
    const int cur = ks & 1;
    if (ks < 4) {
      #pragma unroll
      for (int nt = 0; nt < 5; ++nt) {
        int row = wn * 80 + nt * 16 + lo4;
        bql[cur ^ 1][nt] = *(const short8*)(W2T + row * H_PAD + (ks + 1) * 32 + hi2 * 8);
      }
    }
    short8 af[4];
    #pragma unroll
    for (int mt = 0; mt < 4; ++mt) {
      int row = wm * 64 + mt * 16 + lo4;
      int kb = (ks & 1) * 64 + hi2 * 16;
      af[mt] = *((const short8*)(Hb + (ks >> 1) * 16384 + row * 128 + (kb ^ ((row & 7) << 4))));
    }
    __builtin_amdgcn_s_setprio(1);
    #pragma unroll
    for (int mt = 0; mt < 4; ++mt)
      #pragma unroll
      for (int nt = 0; nt < 5; ++nt)
        acc2[mt][nt] = __builtin_amdgcn_mfma_f32_16x16x32_bf16(af[mt], bql[cur][nt], acc2[mt][nt], 0, 0, 0);
    __builtin_amdgcn_s_setprio(0);
  }

  // ---- epilogue 2: s = relu(acc2 + b2) @ W3, reduce, emit ----
  float sp[4][4];
  #pragma unroll
  for (int mt = 0; mt < 4; ++mt)
    #pragma unroll
    for (int r = 0; r < 4; ++r) sp[mt][r] = 0.f;

  #pragma unroll
  for (int nt = 0; nt < 5; ++nt) {
    int h = wn * 80 + nt * 16 + lo4;
    float w3 = (h < H_DIM) ? W3[h] : 0.f;
    float bb = (h < H_DIM) ? b2[h] : 0.f;
    #pragma unroll
    for (int mt = 0; mt < 4; ++mt)
      #pragma unroll
      for (int r = 0; r < 4; ++r) {
        float hv = fmaxf(acc2[mt][nt][r] + bb, 0.f);
        sp[mt][r] += hv * w3;
      }
  }
  #pragma unroll
  for (int mt = 0; mt < 4; ++mt)
    #pragma unroll
    for (int r = 0; r < 4; ++r) {
      float v = sp[mt][r];
      v += __shfl_xor(v, 1);
      v += __shfl_xor(v, 2);
      v += __shfl_xor(v, 4);
      v += __shfl_xor(v, 8);
      sp[mt][r] = v;
    }
  if (lo4 == 0) {
    #pragma unroll
    for (int mt = 0; mt < 4; ++mt)
      #pragma unroll
      for (int r = 0; r < 4; ++r) {
        int m = wm * 64 + mt * 16 + hi2 * 4 + r;
        s_buf[wn][m] = sp[mt][r];
      }
  }
  __syncthreads();

  if (tid < K_WIN) {
    int m = tid;
    int jr = i - K_WIN + m;
    float sij = si[i] + sj_s[m] + s_buf[0][m] + s_buf[1][m] + b3[0];
    out[i * OUT_C + m] = (jr >= 0) ? sij : 0.f;
  }
  if (tid == K_WIN) out[i * OUT_C + K_WIN] = 0.f;
}

// ---------------------------------------------------------------------------
extern "C" void kernel_launch(void* const* d_in, const int* in_sizes, int n_in,
                              void* d_out, int out_size, void* d_ws, size_t ws_size,
                              hipStream_t stream) {
  const float* g  = (const float*)d_in[0];
  const float* si = (const float*)d_in[1];
  const int*   i1 = (const int*)d_in[2];
  const int*   i2 = (const int*)d_in[3];
  const float* de = (const float*)d_in[4];
  const float* W1 = (const float*)d_in[5];
  const float* b1 = (const float*)d_in[6];
  const float* W2 = (const float*)d_in[7];
  const float* b2 = (const float*)d_in[8];
  const float* W3 = (const float*)d_in[9];
  const float* b3 = (const float*)d_in[10];
  float* out = (float*)d_out;

  char* ws = (char*)d_ws;
  short* g_bf  = (short*)(ws);                 // 1,310,720
  short* W1cT  = (short*)(ws + 1310720);       //   204,800
  short* W1abT = (short*)(ws + 1515520);       //   409,600
  short* W2T   = (short*)(ws + 1925120);       //    51,200
  float* U     = (float*)(ws + 1976320);       //   655,360
  float* V     = (float*)(ws + 2631680);       //   655,360
  float* deW   = (float*)(ws + 3287040);       //     5,760
  short* W1cF  = (short*)(ws + 3292800);       //   204,800  (total ~3.50 MB)

  prep_pack<<<321, 256, 0, stream>>>(g, W1, W2, de, g_bf, W1cT, W1abT, W2T, deW);
  prep_uv_mfma<<<dim3(37, 2), 256, 0, stream>>>(g_bf, W1abT, W1cT, b1, U, V, W1cF);
  pair_main<<<N_PTS, 256, 0, stream>>>(g_bf, W1cF, W2T, U, V, deW,
                                       si, i1, i2, W3, b2, b3, out);
}